// Round 1
// baseline (20947.491 us; speedup 1.0000x reference)
//
#include <hip/hip_runtime.h>
#include <hip/hip_bf16.h>

// Problem constants (match reference)
#define NN_NODES 100000
#define NN_EDGES 600000
#define CC 128
#define NL 3
#define NS 10

// ---------------- CSR build ----------------

__global__ __launch_bounds__(256) void count_deg(const int* __restrict__ dst,
                                                 int* __restrict__ deg) {
    int e = blockIdx.x * 256 + threadIdx.x;
    if (e < NN_EDGES) atomicAdd(&deg[dst[e]], 1);
}

// 1024 elems per block, 98 blocks covers 100000
__global__ __launch_bounds__(256) void scan1(const int* __restrict__ deg,
                                             int* __restrict__ out,
                                             int* __restrict__ partials) {
    __shared__ int lds[256];
    int t = threadIdx.x, b = blockIdx.x;
    int base = b * 1024 + t * 4;
    int v[4];
    int tsum = 0;
#pragma unroll
    for (int i = 0; i < 4; i++) {
        int idx = base + i;
        v[i] = (idx < NN_NODES) ? deg[idx] : 0;
        tsum += v[i];
    }
    lds[t] = tsum;
    __syncthreads();
    for (int off = 1; off < 256; off <<= 1) {
        int xv = (t >= off) ? lds[t - off] : 0;
        __syncthreads();
        lds[t] += xv;
        __syncthreads();
    }
    int run = lds[t] - tsum;  // exclusive prefix for this thread
    if (t == 255) partials[b] = lds[255];
#pragma unroll
    for (int i = 0; i < 4; i++) {
        int idx = base + i;
        if (idx < NN_NODES) out[idx] = run;
        run += v[i];
    }
}

__global__ __launch_bounds__(128) void scan2(int* __restrict__ partials) {
    __shared__ int lds[128];
    int t = threadIdx.x;
    int v = (t < 98) ? partials[t] : 0;
    lds[t] = v;
    __syncthreads();
    for (int off = 1; off < 128; off <<= 1) {
        int xv = (t >= off) ? lds[t - off] : 0;
        __syncthreads();
        lds[t] += xv;
        __syncthreads();
    }
    if (t < 98) partials[t] = lds[t] - v;  // exclusive
    if (t == 127) partials[98] = lds[127]; // total (= NN_EDGES)
}

__global__ __launch_bounds__(256) void scan3(int* __restrict__ offsets,
                                             const int* __restrict__ partials) {
    int b = blockIdx.x;
    int add = partials[b];
    int base = b * 1024 + threadIdx.x * 4;
#pragma unroll
    for (int i = 0; i < 4; i++) {
        int idx = base + i;
        if (idx < NN_NODES) offsets[idx] += add;
    }
    if (b == 0 && threadIdx.x == 0) offsets[NN_NODES] = partials[98];
}

__global__ __launch_bounds__(256) void fill_csr(const int* __restrict__ src,
                                                const int* __restrict__ dst,
                                                const int* __restrict__ offs,
                                                int* __restrict__ cursor,
                                                int* __restrict__ csr) {
    int e = blockIdx.x * 256 + threadIdx.x;
    if (e < NN_EDGES) {
        int d = dst[e];
        int pos = atomicAdd(&cursor[d], 1);
        csr[offs[d] + pos] = src[e];
    }
}

// ---------------- weight transpose ([384][128] -> [128][384]) ----------------

__global__ __launch_bounds__(256) void transpose_weights(const float* __restrict__ wih,
                                                         const float* __restrict__ whh,
                                                         float* __restrict__ wiT,
                                                         float* __restrict__ whT) {
    int l = blockIdx.y;
    const float* s = (blockIdx.z == 0 ? wih : whh) + (size_t)l * 384 * 128;
    float* d = (blockIdx.z == 0 ? wiT : whT) + (size_t)l * 128 * 384;
    int idx = blockIdx.x * 256 + threadIdx.x;  // 0..49151
    int r = idx >> 7, k = idx & 127;
    d[k * 384 + r] = s[idx];
}

// ---------------- m = h @ W  (W is [128][128], NN layout) ----------------
// block = 256 threads, 16 nodes/block; thread: nt = tid>>6 (4 nodes), ct = tid&63 (2 cols)

__global__ __launch_bounds__(256) void gemm_m(const float* __restrict__ h,
                                              const float* __restrict__ w,
                                              float* __restrict__ mbuf) {
    __shared__ float hs[16][CC];
    int tid = threadIdx.x, blk = blockIdx.x;
    const float4* hb = (const float4*)(h + (size_t)blk * 16 * CC);
    float4* hl = (float4*)&hs[0][0];
    hl[tid] = hb[tid];
    hl[tid + 256] = hb[tid + 256];
    __syncthreads();
    int ct = tid & 63, nt = tid >> 6;
    int c0 = ct << 1;
    float acc[4][2] = {};
    for (int k = 0; k < CC; k += 4) {
        float av[4][4];
#pragma unroll
        for (int i = 0; i < 4; i++)
            *(float4*)av[i] = *(const float4*)&hs[nt + 4 * i][k];
#pragma unroll
        for (int kk = 0; kk < 4; kk++) {
            float2 wv = *(const float2*)&w[(size_t)(k + kk) * CC + c0];
#pragma unroll
            for (int i = 0; i < 4; i++) {
                acc[i][0] = fmaf(av[i][kk], wv.x, acc[i][0]);
                acc[i][1] = fmaf(av[i][kk], wv.y, acc[i][1]);
            }
        }
    }
#pragma unroll
    for (int i = 0; i < 4; i++) {
        size_t n = (size_t)blk * 16 + nt + 4 * i;
        *(float2*)&mbuf[n * CC + c0] = make_float2(acc[i][0], acc[i][1]);
    }
}

// ---------------- agg[n] = sum_{e in-edges(n)} m[src[e]] ----------------
// 32 threads per node (float4 over 128 cols), 8 nodes/block

__global__ __launch_bounds__(256) void gather_agg(const float* __restrict__ mbuf,
                                                  const int* __restrict__ offs,
                                                  const int* __restrict__ csr,
                                                  float* __restrict__ agg) {
    int tid = threadIdx.x;
    int node = blockIdx.x * 8 + (tid >> 5);
    int c4 = (tid & 31) << 2;
    int b = offs[node], e = offs[node + 1];
    float ax = 0.f, ay = 0.f, az = 0.f, aw = 0.f;
    for (int j = b; j < e; j++) {
        int s = csr[j];
        float4 v = *(const float4*)&mbuf[(size_t)s * CC + c4];
        ax += v.x; ay += v.y; az += v.z; aw += v.w;
    }
    *(float4*)&agg[(size_t)node * CC + c4] = make_float4(ax, ay, az, aw);
}

// ---------------- fused GRU gates; h updated in place ----------------
// gi = agg@WiT + bi ; gh = h@WhT + bh ; GRU blend; optional ReLU.
// block = 256 threads, 16 nodes/block; thread: nt = tid>>6 (4 nodes), ct = tid&63 (2 cols)

__global__ __launch_bounds__(256) void gates_fused(const float* __restrict__ agg,
                                                   float* __restrict__ h,
                                                   const float* __restrict__ wiT,
                                                   const float* __restrict__ whT,
                                                   const float* __restrict__ bi,
                                                   const float* __restrict__ bh,
                                                   int relu) {
    __shared__ float as_[16][CC];
    __shared__ float hsh[16][CC];
    int tid = threadIdx.x, blk = blockIdx.x;
    const float4* ab = (const float4*)(agg + (size_t)blk * 16 * CC);
    const float4* hb = (const float4*)(h + (size_t)blk * 16 * CC);
    float4* al = (float4*)&as_[0][0];
    float4* hl = (float4*)&hsh[0][0];
    al[tid] = ab[tid];
    al[tid + 256] = ab[tid + 256];
    hl[tid] = hb[tid];
    hl[tid + 256] = hb[tid + 256];
    __syncthreads();
    int ct = tid & 63, nt = tid >> 6;
    int c0 = ct << 1;

    float air[4][2] = {}, aiz[4][2] = {}, ain[4][2] = {};
    float ahr[4][2] = {}, ahz[4][2] = {}, ahn[4][2] = {};

    for (int k = 0; k < CC; k += 4) {
        float aa[4][4], ha[4][4];
#pragma unroll
        for (int i = 0; i < 4; i++) {
            *(float4*)aa[i] = *(const float4*)&as_[nt + 4 * i][k];
            *(float4*)ha[i] = *(const float4*)&hsh[nt + 4 * i][k];
        }
#pragma unroll
        for (int kk = 0; kk < 4; kk++) {
            const float* wr = wiT + (size_t)(k + kk) * 384;
            const float* hr = whT + (size_t)(k + kk) * 384;
            float2 wir = *(const float2*)&wr[c0];
            float2 wiz = *(const float2*)&wr[128 + c0];
            float2 win = *(const float2*)&wr[256 + c0];
            float2 whr = *(const float2*)&hr[c0];
            float2 whz = *(const float2*)&hr[128 + c0];
            float2 whn = *(const float2*)&hr[256 + c0];
#pragma unroll
            for (int i = 0; i < 4; i++) {
                float a = aa[i][kk], hh = ha[i][kk];
                air[i][0] = fmaf(a, wir.x, air[i][0]);
                air[i][1] = fmaf(a, wir.y, air[i][1]);
                aiz[i][0] = fmaf(a, wiz.x, aiz[i][0]);
                aiz[i][1] = fmaf(a, wiz.y, aiz[i][1]);
                ain[i][0] = fmaf(a, win.x, ain[i][0]);
                ain[i][1] = fmaf(a, win.y, ain[i][1]);
                ahr[i][0] = fmaf(hh, whr.x, ahr[i][0]);
                ahr[i][1] = fmaf(hh, whr.y, ahr[i][1]);
                ahz[i][0] = fmaf(hh, whz.x, ahz[i][0]);
                ahz[i][1] = fmaf(hh, whz.y, ahz[i][1]);
                ahn[i][0] = fmaf(hh, whn.x, ahn[i][0]);
                ahn[i][1] = fmaf(hh, whn.y, ahn[i][1]);
            }
        }
    }

    float2 bir = *(const float2*)&bi[c0];
    float2 biz = *(const float2*)&bi[128 + c0];
    float2 bin = *(const float2*)&bi[256 + c0];
    float2 bhr = *(const float2*)&bh[c0];
    float2 bhz = *(const float2*)&bh[128 + c0];
    float2 bhn = *(const float2*)&bh[256 + c0];

#pragma unroll
    for (int i = 0; i < 4; i++) {
        int row = nt + 4 * i;
        size_t n = (size_t)blk * 16 + row;
        float out0, out1;
        {
            float ir = air[i][0] + bir.x, iz = aiz[i][0] + biz.x, inn = ain[i][0] + bin.x;
            float hrv = ahr[i][0] + bhr.x, hzv = ahz[i][0] + bhz.x, hnv = ahn[i][0] + bhn.x;
            float r = 1.f / (1.f + expf(-(ir + hrv)));
            float z = 1.f / (1.f + expf(-(iz + hzv)));
            float nn2 = tanhf(inn + r * hnv);
            float hp = hsh[row][c0];
            float hv = (1.f - z) * nn2 + z * hp;
            if (relu) hv = fmaxf(hv, 0.f);
            out0 = hv;
        }
        {
            float ir = air[i][1] + bir.y, iz = aiz[i][1] + biz.y, inn = ain[i][1] + bin.y;
            float hrv = ahr[i][1] + bhr.y, hzv = ahz[i][1] + bhz.y, hnv = ahn[i][1] + bhn.y;
            float r = 1.f / (1.f + expf(-(ir + hrv)));
            float z = 1.f / (1.f + expf(-(iz + hzv)));
            float nn2 = tanhf(inn + r * hnv);
            float hp = hsh[row][c0 + 1];
            float hv = (1.f - z) * nn2 + z * hp;
            if (relu) hv = fmaxf(hv, 0.f);
            out1 = hv;
        }
        *(float2*)&h[n * CC + c0] = make_float2(out0, out1);
    }
}

// ---------------- launch ----------------

extern "C" void kernel_launch(void* const* d_in, const int* in_sizes, int n_in,
                              void* d_out, int out_size, void* d_ws, size_t ws_size,
                              hipStream_t stream) {
    const float* x = (const float*)d_in[0];
    const int* ei = (const int*)d_in[1];
    const float* weights = (const float*)d_in[2];
    const float* w_ih = (const float*)d_in[3];
    const float* w_hh = (const float*)d_in[4];
    const float* b_ih = (const float*)d_in[5];
    const float* b_hh = (const float*)d_in[6];
    float* h = (float*)d_out;

    const int* src = ei;
    const int* dst = ei + NN_EDGES;

    // workspace carve
    float* mbuf = (float*)d_ws;                         // 12.8M floats
    float* agg = mbuf + (size_t)NN_NODES * CC;          // 12.8M floats
    float* wiT = agg + (size_t)NN_NODES * CC;           // 3*128*384
    float* whT = wiT + (size_t)NL * CC * 384;
    float* endf = whT + (size_t)NL * CC * 384;
    int* deg = (int*)endf;                              // 100000
    int* cursor = deg + NN_NODES;                       // 100000
    int* offsets = cursor + NN_NODES;                   // 100001
    int* csr = offsets + (NN_NODES + 1);                // 600000
    int* partials = csr + NN_EDGES;                     // 99+

    // h <- x
    hipMemcpyAsync(h, x, (size_t)NN_NODES * CC * sizeof(float),
                   hipMemcpyDeviceToDevice, stream);
    // zero deg + cursor (contiguous)
    hipMemsetAsync(deg, 0, (size_t)2 * NN_NODES * sizeof(int), stream);

    const int EB = (NN_EDGES + 255) / 256;
    count_deg<<<EB, 256, 0, stream>>>(dst, deg);
    scan1<<<98, 256, 0, stream>>>(deg, offsets, partials);
    scan2<<<1, 128, 0, stream>>>(partials);
    scan3<<<98, 256, 0, stream>>>(offsets, partials);
    fill_csr<<<EB, 256, 0, stream>>>(src, dst, offsets, cursor, csr);
    transpose_weights<<<dim3(192, NL, 2), 256, 0, stream>>>(w_ih, w_hh, wiT, whT);

    const int NB_NODES16 = NN_NODES / 16;  // 6250
    const int NB_NODES8 = NN_NODES / 8;    // 12500

    for (int l = 0; l < NL; l++) {
        for (int s = 0; s < NS; s++) {
            const float* wls = weights + (size_t)(l * NS + s) * CC * CC;
            gemm_m<<<NB_NODES16, 256, 0, stream>>>(h, wls, mbuf);
            gather_agg<<<NB_NODES8, 256, 0, stream>>>(mbuf, offsets, csr, agg);
            int relu = (s == NS - 1 && l < NL - 1) ? 1 : 0;
            gates_fused<<<NB_NODES16, 256, 0, stream>>>(
                agg, h, wiT + (size_t)l * CC * 384, whT + (size_t)l * CC * 384,
                b_ih + (size_t)l * 384, b_hh + (size_t)l * 384, relu);
        }
    }
    (void)in_sizes; (void)n_in; (void)out_size; (void)ws_size;
}

// Round 3
// 13412.521 us; speedup vs baseline: 1.5618x; 1.5618x over previous
//
#include <hip/hip_runtime.h>
#include <hip/hip_bf16.h>

#define NN_NODES 100000
#define NN_EDGES 600000
#define CC 128
#define NL 3
#define NS 10

// ---------------- CSR build ----------------

__global__ __launch_bounds__(256) void count_deg(const int* __restrict__ dst,
                                                 int* __restrict__ deg) {
    int e = blockIdx.x * 256 + threadIdx.x;
    if (e < NN_EDGES) atomicAdd(&deg[dst[e]], 1);
}

__global__ __launch_bounds__(256) void scan1(const int* __restrict__ deg,
                                             int* __restrict__ out,
                                             int* __restrict__ partials) {
    __shared__ int lds[256];
    int t = threadIdx.x, b = blockIdx.x;
    int base = b * 1024 + t * 4;
    int v[4];
    int tsum = 0;
#pragma unroll
    for (int i = 0; i < 4; i++) {
        int idx = base + i;
        v[i] = (idx < NN_NODES) ? deg[idx] : 0;
        tsum += v[i];
    }
    lds[t] = tsum;
    __syncthreads();
    for (int off = 1; off < 256; off <<= 1) {
        int xv = (t >= off) ? lds[t - off] : 0;
        __syncthreads();
        lds[t] += xv;
        __syncthreads();
    }
    int run = lds[t] - tsum;
    if (t == 255) partials[b] = lds[255];
#pragma unroll
    for (int i = 0; i < 4; i++) {
        int idx = base + i;
        if (idx < NN_NODES) out[idx] = run;
        run += v[i];
    }
}

__global__ __launch_bounds__(128) void scan2(int* __restrict__ partials) {
    __shared__ int lds[128];
    int t = threadIdx.x;
    int v = (t < 98) ? partials[t] : 0;
    lds[t] = v;
    __syncthreads();
    for (int off = 1; off < 128; off <<= 1) {
        int xv = (t >= off) ? lds[t - off] : 0;
        __syncthreads();
        lds[t] += xv;
        __syncthreads();
    }
    if (t < 98) partials[t] = lds[t] - v;
    if (t == 127) partials[98] = lds[127];
}

__global__ __launch_bounds__(256) void scan3(int* __restrict__ offsets,
                                             const int* __restrict__ partials) {
    int b = blockIdx.x;
    int add = partials[b];
    int base = b * 1024 + threadIdx.x * 4;
#pragma unroll
    for (int i = 0; i < 4; i++) {
        int idx = base + i;
        if (idx < NN_NODES) offsets[idx] += add;
    }
    if (b == 0 && threadIdx.x == 0) offsets[NN_NODES] = partials[98];
}

__global__ __launch_bounds__(256) void fill_csr(const int* __restrict__ src,
                                                const int* __restrict__ dst,
                                                const int* __restrict__ offs,
                                                int* __restrict__ cursor,
                                                int* __restrict__ csr) {
    int e = blockIdx.x * 256 + threadIdx.x;
    if (e < NN_EDGES) {
        int d = dst[e];
        int pos = atomicAdd(&cursor[d], 1);
        csr[offs[d] + pos] = src[e];
    }
}

// ---------------- weight / bias packing (fp32, gate-interleaved) ----------------
// wcat[l][k][c*4+g], k in [0,256), c in [0,128):
//   g=0 (r):  k<128 ? wi[c][k]       : wh[c][k-128]
//   g=1 (z):  k<128 ? wi[128+c][k]   : wh[128+c][k-128]
//   g=2 (in): k<128 ? wi[256+c][k]   : 0
//   g=3 (hn): k<128 ? 0              : wh[256+c][k-128]

__global__ __launch_bounds__(256) void pack_wcat_f32(const float* __restrict__ wih,
                                                     const float* __restrict__ whh,
                                                     float* __restrict__ wcat) {
    int idx = blockIdx.x * 256 + threadIdx.x;   // NL*256*512 = 393216
    if (idx >= NL * 256 * 512) return;
    int u = idx & 511, k = (idx >> 9) & 255, l = idx >> 17;
    int c = u >> 2, g = u & 3;
    const float* wi = wih + (size_t)l * 384 * CC;
    const float* wh = whh + (size_t)l * 384 * CC;
    float v;
    if (g == 0)      v = (k < 128) ? wi[(size_t)c * CC + k]         : wh[(size_t)c * CC + (k - 128)];
    else if (g == 1) v = (k < 128) ? wi[(size_t)(128 + c) * CC + k] : wh[(size_t)(128 + c) * CC + (k - 128)];
    else if (g == 2) v = (k < 128) ? wi[(size_t)(256 + c) * CC + k] : 0.f;
    else             v = (k < 128) ? 0.f : wh[(size_t)(256 + c) * CC + (k - 128)];
    wcat[idx] = v;
}

__global__ __launch_bounds__(256) void pack_bias_f32(const float* __restrict__ bih,
                                                     const float* __restrict__ bhh,
                                                     float* __restrict__ bpack) {
    int idx = blockIdx.x * 256 + threadIdx.x;   // NL*512
    if (idx >= NL * 512) return;
    int u = idx & 511, l = idx >> 9;
    int c = u >> 2, g = u & 3;
    const float* bi = bih + (size_t)l * 384;
    const float* bh = bhh + (size_t)l * 384;
    float v;
    if (g == 0)      v = bi[c] + bh[c];
    else if (g == 1) v = bi[128 + c] + bh[128 + c];
    else if (g == 2) v = bi[256 + c];
    else             v = bh[256 + c];
    bpack[idx] = v;
}

// ---------------- m = h @ W (fp32, standalone; used for step 0 only) ----------------
// 32 rows/block, 256 thr; wave owns 8 rows, lane owns 2 cols.

__global__ __launch_bounds__(256) void gemm_m_f32(const float* __restrict__ h,
                                                  const float* __restrict__ w,
                                                  float* __restrict__ mbuf) {
    __shared__ float Hs[32][CC];
    int tid = threadIdx.x;
    size_t nbase = (size_t)blockIdx.x * 32;
    const float4* hg = (const float4*)(h + nbase * CC);
    float4* hl = (float4*)&Hs[0][0];
#pragma unroll
    for (int i = 0; i < 4; i++) hl[tid + i * 256] = hg[tid + i * 256];
    __syncthreads();
    int wave = tid >> 6, lane = tid & 63;
    int row0 = wave * 8, c0 = lane * 2;
    float macc[8][2] = {};
#pragma unroll 4
    for (int k = 0; k < 128; k++) {
        float2 wv = *(const float2*)&w[(size_t)k * CC + c0];
#pragma unroll
        for (int r = 0; r < 8; r++) {
            float a = Hs[row0 + r][k];
            macc[r][0] = fmaf(a, wv.x, macc[r][0]);
            macc[r][1] = fmaf(a, wv.y, macc[r][1]);
        }
    }
#pragma unroll
    for (int r = 0; r < 8; r++)
        *(float2*)&mbuf[(nbase + row0 + r) * CC + c0] = make_float2(macc[r][0], macc[r][1]);
}

// ---------------- agg[n] = sum over in-edges of m[src] (fp32) ----------------

__global__ __launch_bounds__(256) void gather_agg(const float* __restrict__ mbuf,
                                                  const int* __restrict__ offs,
                                                  const int* __restrict__ csr,
                                                  float* __restrict__ agg) {
    int tid = threadIdx.x;
    int node = blockIdx.x * 8 + (tid >> 5);
    int c4 = (tid & 31) << 2;
    int b = offs[node], e = offs[node + 1];
    float ax = 0.f, ay = 0.f, az = 0.f, aw = 0.f;
    for (int j = b; j < e; j++) {
        int s = csr[j];
        float4 v = *(const float4*)&mbuf[(size_t)s * CC + c4];
        ax += v.x; ay += v.y; az += v.z; aw += v.w;
    }
    *(float4*)&agg[(size_t)node * CC + c4] = make_float4(ax, ay, az, aw);
}

// ---------------- fused gates + next-step m (fp32) ----------------
// 32 nodes/block, 256 thr (4 waves). Wave owns rows [wave*8, wave*8+8);
// lane owns output cols {lane*2, lane*2+1}, with all 4 gates interleaved in B.
// After GRU epilogue, h_new is staged in LDS (reusing As) and m_next = h_new @ wnext
// is computed in the same block.

#define GEMM_HALF(SMEM, KOFF)                                               \
    _Pragma("unroll 2")                                                     \
    for (int k = 0; k < 128; k++) {                                         \
        const float* bp = &wcat[((size_t)(KOFF + k)) * 512 + lane * 8];     \
        float4 b0 = *(const float4*)bp;                                     \
        float4 b1 = *(const float4*)(bp + 4);                               \
        _Pragma("unroll")                                                   \
        for (int r = 0; r < 8; r++) {                                       \
            float a = SMEM[row0 + r][k];                                    \
            acc[0][0][r] = fmaf(a, b0.x, acc[0][0][r]);                     \
            acc[0][1][r] = fmaf(a, b0.y, acc[0][1][r]);                     \
            acc[0][2][r] = fmaf(a, b0.z, acc[0][2][r]);                     \
            acc[0][3][r] = fmaf(a, b0.w, acc[0][3][r]);                     \
            acc[1][0][r] = fmaf(a, b1.x, acc[1][0][r]);                     \
            acc[1][1][r] = fmaf(a, b1.y, acc[1][1][r]);                     \
            acc[1][2][r] = fmaf(a, b1.z, acc[1][2][r]);                     \
            acc[1][3][r] = fmaf(a, b1.w, acc[1][3][r]);                     \
        }                                                                   \
    }

__global__ __launch_bounds__(256) void gates_step(const float* __restrict__ agg,
                                                  float* __restrict__ h,
                                                  const float* __restrict__ wcat,
                                                  const float* __restrict__ bpk,
                                                  const float* __restrict__ wnext,
                                                  float* __restrict__ mbuf,
                                                  int relu, int has_next) {
    __shared__ float As[32][CC];   // agg tile; reused for h_new before m-phase
    __shared__ float Hs[32][CC];   // h tile
    int tid = threadIdx.x;
    size_t nbase = (size_t)blockIdx.x * 32;
    {
        const float4* ag = (const float4*)(agg + nbase * CC);
        const float4* hg = (const float4*)(h + nbase * CC);
        float4* al = (float4*)&As[0][0];
        float4* hl = (float4*)&Hs[0][0];
#pragma unroll
        for (int i = 0; i < 4; i++) {
            al[tid + i * 256] = ag[tid + i * 256];
            hl[tid + i * 256] = hg[tid + i * 256];
        }
    }
    __syncthreads();
    int wave = tid >> 6, lane = tid & 63;
    int row0 = wave * 8, c0 = lane * 2;

    float acc[2][4][8] = {};   // [cj][gate][row] — all indices static after unroll
    GEMM_HALF(As, 0)     // k 0..127   : A = agg
    GEMM_HALF(Hs, 128)   // k 128..255 : A = h

    float4 bb0 = *(const float4*)&bpk[c0 * 4];
    float4 bb1 = *(const float4*)&bpk[(c0 + 1) * 4];

#pragma unroll
    for (int r = 0; r < 8; r++) {
        int row = row0 + r;
        float hv[2];
#pragma unroll
        for (int cj = 0; cj < 2; cj++) {
            float4 bb = cj ? bb1 : bb0;
            float rr = 1.f / (1.f + expf(-(acc[cj][0][r] + bb.x)));
            float zz = 1.f / (1.f + expf(-(acc[cj][1][r] + bb.y)));
            float nn = tanhf(acc[cj][2][r] + bb.z + rr * (acc[cj][3][r] + bb.w));
            float hp = Hs[row][c0 + cj];
            float v = (1.f - zz) * nn + zz * hp;
            if (relu) v = fmaxf(v, 0.f);
            hv[cj] = v;
        }
        *(float2*)&h[(nbase + row) * CC + c0] = make_float2(hv[0], hv[1]);
        As[row][c0] = hv[0];
        As[row][c0 + 1] = hv[1];
    }
    __syncthreads();

    if (has_next) {
        float macc[8][2] = {};
#pragma unroll 4
        for (int k = 0; k < 128; k++) {
            float2 wv = *(const float2*)&wnext[(size_t)k * CC + c0];
#pragma unroll
            for (int r = 0; r < 8; r++) {
                float a = As[row0 + r][k];
                macc[r][0] = fmaf(a, wv.x, macc[r][0]);
                macc[r][1] = fmaf(a, wv.y, macc[r][1]);
            }
        }
#pragma unroll
        for (int r = 0; r < 8; r++)
            *(float2*)&mbuf[(nbase + row0 + r) * CC + c0] = make_float2(macc[r][0], macc[r][1]);
    }
}

// ---------------- launch ----------------

extern "C" void kernel_launch(void* const* d_in, const int* in_sizes, int n_in,
                              void* d_out, int out_size, void* d_ws, size_t ws_size,
                              hipStream_t stream) {
    const float* x = (const float*)d_in[0];
    const int* ei = (const int*)d_in[1];
    const float* weights = (const float*)d_in[2];
    const float* w_ih = (const float*)d_in[3];
    const float* w_hh = (const float*)d_in[4];
    const float* b_ih = (const float*)d_in[5];
    const float* b_hh = (const float*)d_in[6];
    float* h = (float*)d_out;

    const int* src = ei;
    const int* dst = ei + NN_EDGES;

    // workspace carve
    float* mbuf = (float*)d_ws;                          // 12.8M floats
    float* agg = mbuf + (size_t)NN_NODES * CC;           // 12.8M floats
    float* wcat = agg + (size_t)NN_NODES * CC;           // 3*131072
    float* bpack = wcat + (size_t)NL * 131072;           // 3*512
    float* endf = bpack + NL * 512;
    int* deg = (int*)endf;                               // 100000
    int* cursor = deg + NN_NODES;                        // 100000
    int* offsets = cursor + NN_NODES;                    // 100001
    int* csr = offsets + (NN_NODES + 1);                 // 600000
    int* partials = csr + NN_EDGES;                      // 99+

    hipMemcpyAsync(h, x, (size_t)NN_NODES * CC * sizeof(float),
                   hipMemcpyDeviceToDevice, stream);
    hipMemsetAsync(deg, 0, (size_t)2 * NN_NODES * sizeof(int), stream);

    const int EB = (NN_EDGES + 255) / 256;
    count_deg<<<EB, 256, 0, stream>>>(dst, deg);
    scan1<<<98, 256, 0, stream>>>(deg, offsets, partials);
    scan2<<<1, 128, 0, stream>>>(partials);
    scan3<<<98, 256, 0, stream>>>(offsets, partials);
    fill_csr<<<EB, 256, 0, stream>>>(src, dst, offsets, cursor, csr);
    pack_wcat_f32<<<1536, 256, 0, stream>>>(w_ih, w_hh, wcat);
    pack_bias_f32<<<6, 256, 0, stream>>>(b_ih, b_hh, bpack);

    const int GB = NN_NODES / 32;       // 3125
    const int GB_GATH = NN_NODES / 8;   // 12500

    // m for (l=0, s=0)
    gemm_m_f32<<<GB, 256, 0, stream>>>(h, weights, mbuf);

    for (int l = 0; l < NL; l++) {
        for (int s = 0; s < NS; s++) {
            gather_agg<<<GB_GATH, 256, 0, stream>>>(mbuf, offsets, csr, agg);
            int relu = (s == NS - 1 && l < NL - 1) ? 1 : 0;
            int has_next = !(l == NL - 1 && s == NS - 1);
            const float* wnext;
            if (s < NS - 1)      wnext = weights + (size_t)(l * NS + s + 1) * CC * CC;
            else if (l < NL - 1) wnext = weights + (size_t)((l + 1) * NS) * CC * CC;
            else                 wnext = weights;  // unused (has_next == 0)
            gates_step<<<GB, 256, 0, stream>>>(
                agg, h, wcat + (size_t)l * 131072, bpack + (size_t)l * 512,
                wnext, mbuf, relu, has_next);
        }
    }
    (void)in_sizes; (void)n_in; (void)out_size; (void)ws_size;
}

// Round 4
// 11699.828 us; speedup vs baseline: 1.7904x; 1.1464x over previous
//
#include <hip/hip_runtime.h>
#include <hip/hip_bf16.h>

#define NN_NODES 100000
#define NN_EDGES 600000
#define CC 128
#define NL 3
#define NS 10

// ---------------- CSR build ----------------

__global__ __launch_bounds__(256) void count_deg(const int* __restrict__ dst,
                                                 int* __restrict__ deg) {
    int e = blockIdx.x * 256 + threadIdx.x;
    if (e < NN_EDGES) atomicAdd(&deg[dst[e]], 1);
}

__global__ __launch_bounds__(256) void scan1(const int* __restrict__ deg,
                                             int* __restrict__ out,
                                             int* __restrict__ partials) {
    __shared__ int lds[256];
    int t = threadIdx.x, b = blockIdx.x;
    int base = b * 1024 + t * 4;
    int v[4];
    int tsum = 0;
#pragma unroll
    for (int i = 0; i < 4; i++) {
        int idx = base + i;
        v[i] = (idx < NN_NODES) ? deg[idx] : 0;
        tsum += v[i];
    }
    lds[t] = tsum;
    __syncthreads();
    for (int off = 1; off < 256; off <<= 1) {
        int xv = (t >= off) ? lds[t - off] : 0;
        __syncthreads();
        lds[t] += xv;
        __syncthreads();
    }
    int run = lds[t] - tsum;
    if (t == 255) partials[b] = lds[255];
#pragma unroll
    for (int i = 0; i < 4; i++) {
        int idx = base + i;
        if (idx < NN_NODES) out[idx] = run;
        run += v[i];
    }
}

__global__ __launch_bounds__(128) void scan2(int* __restrict__ partials) {
    __shared__ int lds[128];
    int t = threadIdx.x;
    int v = (t < 98) ? partials[t] : 0;
    lds[t] = v;
    __syncthreads();
    for (int off = 1; off < 128; off <<= 1) {
        int xv = (t >= off) ? lds[t - off] : 0;
        __syncthreads();
        lds[t] += xv;
        __syncthreads();
    }
    if (t < 98) partials[t] = lds[t] - v;
    if (t == 127) partials[98] = lds[127];
}

__global__ __launch_bounds__(256) void scan3(int* __restrict__ offsets,
                                             const int* __restrict__ partials) {
    int b = blockIdx.x;
    int add = partials[b];
    int base = b * 1024 + threadIdx.x * 4;
#pragma unroll
    for (int i = 0; i < 4; i++) {
        int idx = base + i;
        if (idx < NN_NODES) offsets[idx] += add;
    }
    if (b == 0 && threadIdx.x == 0) offsets[NN_NODES] = partials[98];
}

__global__ __launch_bounds__(256) void fill_csr(const int* __restrict__ src,
                                                const int* __restrict__ dst,
                                                const int* __restrict__ offs,
                                                int* __restrict__ cursor,
                                                int* __restrict__ csr) {
    int e = blockIdx.x * 256 + threadIdx.x;
    if (e < NN_EDGES) {
        int d = dst[e];
        int pos = atomicAdd(&cursor[d], 1);
        csr[offs[d] + pos] = src[e];
    }
}

// ---------------- weight / bias packing (fp32, zero-free) ----------------
// wrz[l][k][c*2+g], k in [0,256), c in [0,128), g in {0=r,1=z}:
//   g=0: k<128 ? wi[c][k]      : wh[c][k-128]
//   g=1: k<128 ? wi[128+c][k]  : wh[128+c][k-128]
// win[l][k][c] = wi[256+c][k]  (k in [0,128))
// whn[l][k][c] = wh[256+c][k]

__global__ __launch_bounds__(256) void pack_wrz(const float* __restrict__ wih,
                                                const float* __restrict__ whh,
                                                float* __restrict__ wrz) {
    int idx = blockIdx.x * 256 + threadIdx.x;   // NL*256*256 = 196608
    if (idx >= NL * 256 * 256) return;
    int u = idx & 255, k = (idx >> 8) & 255, l = idx >> 16;
    int c = u >> 1, g = u & 1;
    const float* wi = wih + (size_t)l * 384 * CC;
    const float* wh = whh + (size_t)l * 384 * CC;
    int row = g ? (128 + c) : c;
    float v = (k < 128) ? wi[(size_t)row * CC + k] : wh[(size_t)row * CC + (k - 128)];
    wrz[idx] = v;
}

__global__ __launch_bounds__(256) void pack_winhn(const float* __restrict__ wih,
                                                  const float* __restrict__ whh,
                                                  float* __restrict__ win,
                                                  float* __restrict__ whn) {
    int idx = blockIdx.x * 256 + threadIdx.x;   // NL*128*128 = 49152
    if (idx >= NL * 128 * 128) return;
    int c = idx & 127, k = (idx >> 7) & 127, l = idx >> 14;
    const float* wi = wih + (size_t)l * 384 * CC;
    const float* wh = whh + (size_t)l * 384 * CC;
    win[idx] = wi[(size_t)(256 + c) * CC + k];
    whn[idx] = wh[(size_t)(256 + c) * CC + k];
}

// bpack[l][c*4+{0,1,2,3}] = {bi[c]+bh[c], bi[128+c]+bh[128+c], bi[256+c], bh[256+c]}
__global__ __launch_bounds__(256) void pack_bias_f32(const float* __restrict__ bih,
                                                     const float* __restrict__ bhh,
                                                     float* __restrict__ bpack) {
    int idx = blockIdx.x * 256 + threadIdx.x;   // NL*512
    if (idx >= NL * 512) return;
    int u = idx & 511, l = idx >> 9;
    int c = u >> 2, g = u & 3;
    const float* bi = bih + (size_t)l * 384;
    const float* bh = bhh + (size_t)l * 384;
    float v;
    if (g == 0)      v = bi[c] + bh[c];
    else if (g == 1) v = bi[128 + c] + bh[128 + c];
    else if (g == 2) v = bi[256 + c];
    else             v = bh[256 + c];
    bpack[idx] = v;
}

// ---------------- m = h @ W (fp32, standalone; step 0 only) ----------------

__global__ __launch_bounds__(256, 2) void gemm_m_f32(const float* __restrict__ h,
                                                     const float* __restrict__ w,
                                                     float* __restrict__ mbuf) {
    __shared__ float Hs[32][CC];
    int tid = threadIdx.x;
    size_t nbase = (size_t)blockIdx.x * 32;
    const float4* hg = (const float4*)(h + nbase * CC);
    float4* hl = (float4*)&Hs[0][0];
#pragma unroll
    for (int i = 0; i < 4; i++) hl[tid + i * 256] = hg[tid + i * 256];
    __syncthreads();
    int wave = tid >> 6, lane = tid & 63;
    int row0 = wave * 8, c0 = lane * 2;
    float macc[8][2] = {};
#pragma unroll 4
    for (int k = 0; k < 128; k++) {
        float2 wv = *(const float2*)&w[(size_t)k * CC + c0];
#pragma unroll
        for (int r = 0; r < 8; r++) {
            float a = Hs[row0 + r][k];
            macc[r][0] = fmaf(a, wv.x, macc[r][0]);
            macc[r][1] = fmaf(a, wv.y, macc[r][1]);
        }
    }
#pragma unroll
    for (int r = 0; r < 8; r++)
        *(float2*)&mbuf[(nbase + row0 + r) * CC + c0] = make_float2(macc[r][0], macc[r][1]);
}

// ---------------- agg[n] = sum over in-edges of m[src] (fp32) ----------------

__global__ __launch_bounds__(256) void gather_agg(const float* __restrict__ mbuf,
                                                  const int* __restrict__ offs,
                                                  const int* __restrict__ csr,
                                                  float* __restrict__ agg) {
    int tid = threadIdx.x;
    int node = blockIdx.x * 8 + (tid >> 5);
    int c4 = (tid & 31) << 2;
    int b = offs[node], e = offs[node + 1];
    float ax = 0.f, ay = 0.f, az = 0.f, aw = 0.f;
    for (int j = b; j < e; j++) {
        int s = csr[j];
        float4 v = *(const float4*)&mbuf[(size_t)s * CC + c4];
        ax += v.x; ay += v.y; az += v.z; aw += v.w;
    }
    *(float4*)&agg[(size_t)node * CC + c4] = make_float4(ax, ay, az, aw);
}

// ---------------- fused gates + next-step m (fp32, zero-free) ----------------
// 32 nodes/block, 256 thr (4 waves). Wave owns rows [wave*8, wave*8+8);
// lane owns output cols {lane*2, lane*2+1}.
// rz: K=256 over [agg|h]; in: K=128 over agg; hn: K=128 over h.
// After the GRU epilogue, h_new is staged in LDS (reusing As) and
// m_next = h_new @ wnext is computed in the same block.

__global__ __launch_bounds__(256, 2) void gates_step(const float* __restrict__ agg,
                                                     float* __restrict__ h,
                                                     const float* __restrict__ wrz,
                                                     const float* __restrict__ win,
                                                     const float* __restrict__ whn,
                                                     const float* __restrict__ bpk,
                                                     const float* __restrict__ wnext,
                                                     float* __restrict__ mbuf,
                                                     int relu, int has_next) {
    __shared__ float As[32][CC];   // agg tile; reused for h_new before m-phase
    __shared__ float Hs[32][CC];   // h tile
    int tid = threadIdx.x;
    size_t nbase = (size_t)blockIdx.x * 32;
    {
        const float4* ag = (const float4*)(agg + nbase * CC);
        const float4* hg = (const float4*)(h + nbase * CC);
        float4* al = (float4*)&As[0][0];
        float4* hl = (float4*)&Hs[0][0];
#pragma unroll
        for (int i = 0; i < 4; i++) {
            al[tid + i * 256] = ag[tid + i * 256];
            hl[tid + i * 256] = hg[tid + i * 256];
        }
    }
    __syncthreads();
    int wave = tid >> 6, lane = tid & 63;
    int row0 = wave * 8, c0 = lane * 2;

    float arz[2][2][8] = {};   // [cj][g in {r,z}][row]
    float ain[2][8] = {};      // [cj][row]
    float ahn[2][8] = {};

    // first half: A = agg
#pragma unroll 2
    for (int k = 0; k < 128; k++) {
        float4 brz = *(const float4*)&wrz[(size_t)k * 256 + c0 * 2];
        float2 bi2 = *(const float2*)&win[(size_t)k * CC + c0];
#pragma unroll
        for (int r = 0; r < 8; r++) {
            float a = As[row0 + r][k];
            arz[0][0][r] = fmaf(a, brz.x, arz[0][0][r]);
            arz[0][1][r] = fmaf(a, brz.y, arz[0][1][r]);
            arz[1][0][r] = fmaf(a, brz.z, arz[1][0][r]);
            arz[1][1][r] = fmaf(a, brz.w, arz[1][1][r]);
            ain[0][r] = fmaf(a, bi2.x, ain[0][r]);
            ain[1][r] = fmaf(a, bi2.y, ain[1][r]);
        }
    }
    // second half: A = h
#pragma unroll 2
    for (int k = 0; k < 128; k++) {
        float4 brz = *(const float4*)&wrz[(size_t)(128 + k) * 256 + c0 * 2];
        float2 bh2 = *(const float2*)&whn[(size_t)k * CC + c0];
#pragma unroll
        for (int r = 0; r < 8; r++) {
            float a = Hs[row0 + r][k];
            arz[0][0][r] = fmaf(a, brz.x, arz[0][0][r]);
            arz[0][1][r] = fmaf(a, brz.y, arz[0][1][r]);
            arz[1][0][r] = fmaf(a, brz.z, arz[1][0][r]);
            arz[1][1][r] = fmaf(a, brz.w, arz[1][1][r]);
            ahn[0][r] = fmaf(a, bh2.x, ahn[0][r]);
            ahn[1][r] = fmaf(a, bh2.y, ahn[1][r]);
        }
    }

    float4 bb0 = *(const float4*)&bpk[c0 * 4];          // {br,bz,bin,bhn} col c0
    float4 bb1 = *(const float4*)&bpk[(c0 + 1) * 4];    // col c0+1

#pragma unroll
    for (int r = 0; r < 8; r++) {
        int row = row0 + r;
        float hv[2];
#pragma unroll
        for (int cj = 0; cj < 2; cj++) {
            float4 bb = cj ? bb1 : bb0;
            float rr = 1.f / (1.f + expf(-(arz[cj][0][r] + bb.x)));
            float zz = 1.f / (1.f + expf(-(arz[cj][1][r] + bb.y)));
            float nn = tanhf(ain[cj][r] + bb.z + rr * (ahn[cj][r] + bb.w));
            float hp = Hs[row][c0 + cj];
            float v = (1.f - zz) * nn + zz * hp;
            if (relu) v = fmaxf(v, 0.f);
            hv[cj] = v;
        }
        *(float2*)&h[(nbase + row) * CC + c0] = make_float2(hv[0], hv[1]);
        As[row][c0] = hv[0];
        As[row][c0 + 1] = hv[1];
    }
    __syncthreads();

    if (has_next) {
        float macc[8][2] = {};
#pragma unroll 4
        for (int k = 0; k < 128; k++) {
            float2 wv = *(const float2*)&wnext[(size_t)k * CC + c0];
#pragma unroll
            for (int r = 0; r < 8; r++) {
                float a = As[row0 + r][k];
                macc[r][0] = fmaf(a, wv.x, macc[r][0]);
                macc[r][1] = fmaf(a, wv.y, macc[r][1]);
            }
        }
#pragma unroll
        for (int r = 0; r < 8; r++)
            *(float2*)&mbuf[(nbase + row0 + r) * CC + c0] = make_float2(macc[r][0], macc[r][1]);
    }
}

// ---------------- launch ----------------

extern "C" void kernel_launch(void* const* d_in, const int* in_sizes, int n_in,
                              void* d_out, int out_size, void* d_ws, size_t ws_size,
                              hipStream_t stream) {
    const float* x = (const float*)d_in[0];
    const int* ei = (const int*)d_in[1];
    const float* weights = (const float*)d_in[2];
    const float* w_ih = (const float*)d_in[3];
    const float* w_hh = (const float*)d_in[4];
    const float* b_ih = (const float*)d_in[5];
    const float* b_hh = (const float*)d_in[6];
    float* h = (float*)d_out;

    const int* src = ei;
    const int* dst = ei + NN_EDGES;

    // workspace carve
    float* mbuf = (float*)d_ws;                          // 12.8M floats
    float* agg = mbuf + (size_t)NN_NODES * CC;           // 12.8M floats
    float* wrz = agg + (size_t)NN_NODES * CC;            // NL*65536
    float* win = wrz + (size_t)NL * 65536;               // NL*16384
    float* whn = win + (size_t)NL * 16384;               // NL*16384
    float* bpack = whn + (size_t)NL * 16384;             // NL*512
    float* endf = bpack + NL * 512;
    int* deg = (int*)endf;                               // 100000
    int* cursor = deg + NN_NODES;                        // 100000
    int* offsets = cursor + NN_NODES;                    // 100001
    int* csr = offsets + (NN_NODES + 1);                 // 600000
    int* partials = csr + NN_EDGES;                      // 99+

    hipMemcpyAsync(h, x, (size_t)NN_NODES * CC * sizeof(float),
                   hipMemcpyDeviceToDevice, stream);
    hipMemsetAsync(deg, 0, (size_t)2 * NN_NODES * sizeof(int), stream);

    const int EB = (NN_EDGES + 255) / 256;
    count_deg<<<EB, 256, 0, stream>>>(dst, deg);
    scan1<<<98, 256, 0, stream>>>(deg, offsets, partials);
    scan2<<<1, 128, 0, stream>>>(partials);
    scan3<<<98, 256, 0, stream>>>(offsets, partials);
    fill_csr<<<EB, 256, 0, stream>>>(src, dst, offsets, cursor, csr);
    pack_wrz<<<768, 256, 0, stream>>>(w_ih, w_hh, wrz);
    pack_winhn<<<192, 256, 0, stream>>>(w_ih, w_hh, win, whn);
    pack_bias_f32<<<6, 256, 0, stream>>>(b_ih, b_hh, bpack);

    const int GB = NN_NODES / 32;       // 3125
    const int GB_GATH = NN_NODES / 8;   // 12500

    // m for (l=0, s=0)
    gemm_m_f32<<<GB, 256, 0, stream>>>(h, weights, mbuf);

    for (int l = 0; l < NL; l++) {
        for (int s = 0; s < NS; s++) {
            gather_agg<<<GB_GATH, 256, 0, stream>>>(mbuf, offsets, csr, agg);
            int relu = (s == NS - 1 && l < NL - 1) ? 1 : 0;
            int has_next = !(l == NL - 1 && s == NS - 1);
            const float* wnext;
            if (s < NS - 1)      wnext = weights + (size_t)(l * NS + s + 1) * CC * CC;
            else if (l < NL - 1) wnext = weights + (size_t)((l + 1) * NS) * CC * CC;
            else                 wnext = weights;  // unused (has_next == 0)
            gates_step<<<GB, 256, 0, stream>>>(
                agg, h, wrz + (size_t)l * 65536, win + (size_t)l * 16384,
                whn + (size_t)l * 16384, bpack + (size_t)l * 512,
                wnext, mbuf, relu, has_next);
        }
    }
    (void)in_sizes; (void)n_in; (void)out_size; (void)ws_size;
}

// Round 6
// 6211.592 us; speedup vs baseline: 3.3723x; 1.8835x over previous
//
#include <hip/hip_runtime.h>
#include <hip/hip_bf16.h>

#define NN_NODES 100000
#define NN_PAD   100032
#define NN_EDGES 600000
#define CC 128
#define NL 3
#define NS 10

typedef __attribute__((ext_vector_type(8))) short s16x8;
typedef __attribute__((ext_vector_type(4))) float f32x4;

__device__ __forceinline__ ushort f2bf(float f) {
    union { float f; unsigned u; } v; v.f = f;
    unsigned r = (v.u + 0x7FFFu + ((v.u >> 16) & 1u)) >> 16;
    return (ushort)r;
}
__device__ __forceinline__ float bf2f(ushort u) {
    union { unsigned u; float f; } v; v.u = ((unsigned)u) << 16;
    return v.f;
}
// fp32 -> 3 bf16 planes (v ~= p1 + p2 + p3, residual ~2^-27 rel)
__device__ __forceinline__ void split3(float v, ushort& p1, ushort& p2, ushort& p3) {
    ushort t1 = f2bf(v); float f1 = bf2f(t1);
    float r1 = v - f1;
    ushort t2 = f2bf(r1); float f2 = bf2f(t2);
    ushort t3 = f2bf(r1 - f2);
    p1 = t1; p2 = t2; p3 = t3;
}

// ---------------- CSR build ----------------

__global__ __launch_bounds__(256) void count_deg(const int* __restrict__ dst,
                                                 int* __restrict__ deg) {
    int e = blockIdx.x * 256 + threadIdx.x;
    if (e < NN_EDGES) atomicAdd(&deg[dst[e]], 1);
}

__global__ __launch_bounds__(256) void scan1(const int* __restrict__ deg,
                                             int* __restrict__ out,
                                             int* __restrict__ partials) {
    __shared__ int lds[256];
    int t = threadIdx.x, b = blockIdx.x;
    int base = b * 1024 + t * 4;
    int v[4];
    int tsum = 0;
#pragma unroll
    for (int i = 0; i < 4; i++) {
        int idx = base + i;
        v[i] = (idx < NN_NODES) ? deg[idx] : 0;
        tsum += v[i];
    }
    lds[t] = tsum;
    __syncthreads();
    for (int off = 1; off < 256; off <<= 1) {
        int xv = (t >= off) ? lds[t - off] : 0;
        __syncthreads();
        lds[t] += xv;
        __syncthreads();
    }
    int run = lds[t] - tsum;
    if (t == 255) partials[b] = lds[255];
#pragma unroll
    for (int i = 0; i < 4; i++) {
        int idx = base + i;
        if (idx < NN_NODES) out[idx] = run;
        run += v[i];
    }
}

__global__ __launch_bounds__(128) void scan2(int* __restrict__ partials) {
    __shared__ int lds[128];
    int t = threadIdx.x;
    int v = (t < 98) ? partials[t] : 0;
    lds[t] = v;
    __syncthreads();
    for (int off = 1; off < 128; off <<= 1) {
        int xv = (t >= off) ? lds[t - off] : 0;
        __syncthreads();
        lds[t] += xv;
        __syncthreads();
    }
    if (t < 98) partials[t] = lds[t] - v;
    if (t == 127) partials[98] = lds[127];
}

__global__ __launch_bounds__(256) void scan3(int* __restrict__ offsets,
                                             const int* __restrict__ partials) {
    int b = blockIdx.x;
    int add = partials[b];
    int base = b * 1024 + threadIdx.x * 4;
#pragma unroll
    for (int i = 0; i < 4; i++) {
        int idx = base + i;
        if (idx < NN_NODES) offsets[idx] += add;
    }
    if (b == 0 && threadIdx.x == 0) offsets[NN_NODES] = partials[98];
}

__global__ __launch_bounds__(256) void fill_csr(const int* __restrict__ src,
                                                const int* __restrict__ dst,
                                                const int* __restrict__ offs,
                                                int* __restrict__ cursor,
                                                int* __restrict__ csr) {
    int e = blockIdx.x * 256 + threadIdx.x;
    if (e < NN_EDGES) {
        int d = dst[e];
        int pos = atomicAdd(&cursor[d], 1);
        csr[offs[d] + pos] = src[e];
    }
}

// ---------------- weight packing: bf16x3 planes in B-fragment order ----------------
// wm3 per (l,s): plane pb, chunk ks, n-tile nt: frag[lane][i] = split_pb(W[ks*32+kg*8+i][nt*16+lr])
#define WM_LS (3 * 4 * 8 * 512)

__global__ __launch_bounds__(256) void pack_wm3(const float* __restrict__ w,
                                                ushort* __restrict__ wm3) {
    int idx = blockIdx.x * 256 + threadIdx.x;   // (ls,ks,nt,lane): 30*4*8*64
    if (idx >= NL * NS * 4 * 8 * 64) return;
    int lane = idx & 63, nt = (idx >> 6) & 7, ks = (idx >> 9) & 3, ls = idx >> 11;
    int lr = lane & 15, kg = lane >> 4;
    int k0 = ks * 32 + kg * 8, col = nt * 16 + lr;
    const float* W = w + (size_t)ls * CC * CC;
    ushort o1[8], o2[8], o3[8];
#pragma unroll
    for (int i = 0; i < 8; i++) split3(W[(size_t)(k0 + i) * CC + col], o1[i], o2[i], o3[i]);
    size_t base = (size_t)ls * WM_LS;
    *(s16x8*)&wm3[base + ((size_t)((0 * 4 + ks) * 8 + nt)) * 512 + lane * 8] = *(s16x8*)o1;
    *(s16x8*)&wm3[base + ((size_t)((1 * 4 + ks) * 8 + nt)) * 512 + lane * 8] = *(s16x8*)o2;
    *(s16x8*)&wm3[base + ((size_t)((2 * 4 + ks) * 8 + nt)) * 512 + lane * 8] = *(s16x8*)o3;
}

// gw3 per (mat,l): B[k][u] = mat[u][k], u in [0,384) (rows of w_ih / w_hh are [r|z|n] stacked)
// plane pb, chunk ks, tile (0..23): frag[lane][i] = split_pb(mat[tile*16+lr][ks*32+kg*8+i])
#define GW_ML (3 * 4 * 24 * 512)

__global__ __launch_bounds__(256) void pack_gw3(const float* __restrict__ wih,
                                                const float* __restrict__ whh,
                                                ushort* __restrict__ gw3) {
    int idx = blockIdx.x * 256 + threadIdx.x;   // ((ml*4+ks)*24+tile)*64+lane : 6*4*24*64
    if (idx >= 6 * 4 * 24 * 64) return;
    int lane = idx & 63;
    int t = idx >> 6;
    int tile = t % 24;
    int q = t / 24;
    int ks = q & 3, ml = q >> 2;
    int mat = ml / NL, l = ml % NL;
    int lr = lane & 15, kg = lane >> 4;
    const float* src = (mat ? whh : wih) + (size_t)l * 384 * CC;
    int row = tile * 16 + lr, k0 = ks * 32 + kg * 8;
    ushort o1[8], o2[8], o3[8];
#pragma unroll
    for (int i = 0; i < 8; i++) split3(src[(size_t)row * CC + k0 + i], o1[i], o2[i], o3[i]);
    size_t base = (size_t)ml * GW_ML;
    *(s16x8*)&gw3[base + ((size_t)((0 * 4 + ks) * 24 + tile)) * 512 + lane * 8] = *(s16x8*)o1;
    *(s16x8*)&gw3[base + ((size_t)((1 * 4 + ks) * 24 + tile)) * 512 + lane * 8] = *(s16x8*)o2;
    *(s16x8*)&gw3[base + ((size_t)((2 * 4 + ks) * 24 + tile)) * 512 + lane * 8] = *(s16x8*)o3;
}

// bpack[l][c*4+{0,1,2,3}] = {bi[c]+bh[c], bi[128+c]+bh[128+c], bi[256+c], bh[256+c]}
__global__ __launch_bounds__(256) void pack_bias_f32(const float* __restrict__ bih,
                                                     const float* __restrict__ bhh,
                                                     float* __restrict__ bpack) {
    int idx = blockIdx.x * 256 + threadIdx.x;
    if (idx >= NL * 512) return;
    int u = idx & 511, l = idx >> 9;
    int c = u >> 2, g = u & 3;
    const float* bi = bih + (size_t)l * 384;
    const float* bh = bhh + (size_t)l * 384;
    float v;
    if (g == 0)      v = bi[c] + bh[c];
    else if (g == 1) v = bi[128 + c] + bh[128 + c];
    else if (g == 2) v = bi[256 + c];
    else             v = bh[256 + c];
    bpack[idx] = v;
}

// ---------------- m = h @ W  (bf16x3 MFMA, fp32 in/out) ----------------
// 64 nodes/block, 4 waves; wave owns N-tiles {2w,2w+1}. A split on the fly into
// XOR-swizzled LDS planes (G4: byte ^= (row&7)<<4 breaks the D=128 conflict).

__global__ __launch_bounds__(256, 3) void gemm_m_mfma(const float* __restrict__ h,
                                                      const ushort* __restrict__ wm,
                                                      float* __restrict__ m) {
    __shared__ ushort Ap[3][64 * 128];
    int tid = threadIdx.x;
    size_t nbase = (size_t)blockIdx.x * 64;
    const float4* hg = (const float4*)(h + nbase * CC);
#pragma unroll
    for (int i = 0; i < 8; i++) {
        int fi = tid + i * 256;            // 0..2047
        int row = fi >> 5;
        float4 v = make_float4(0.f, 0.f, 0.f, 0.f);
        if (nbase + row < NN_NODES) v = hg[fi];
        ushort4 s1, s2, s3;
        split3(v.x, s1.x, s2.x, s3.x);
        split3(v.y, s1.y, s2.y, s3.y);
        split3(v.z, s1.z, s2.z, s3.z);
        split3(v.w, s1.w, s2.w, s3.w);
        int boff = row * 256 + ((((fi & 31) * 8)) ^ ((row & 7) << 4));
        *(ushort4*)((char*)&Ap[0][0] + boff) = s1;
        *(ushort4*)((char*)&Ap[1][0] + boff) = s2;
        *(ushort4*)((char*)&Ap[2][0] + boff) = s3;
    }
    __syncthreads();
    int wave = tid >> 6, lane = tid & 63, lr = lane & 15, kg = lane >> 4;
    f32x4 acc[4][2] = {};
#pragma unroll
    for (int ks = 0; ks < 4; ks++) {
        s16x8 a[3][4];
#pragma unroll
        for (int p = 0; p < 3; p++)
#pragma unroll
            for (int mt = 0; mt < 4; mt++) {
                int row = mt * 16 + lr;
                int boff = row * 256 + ((ks * 64 + kg * 16) ^ ((row & 7) << 4));
                a[p][mt] = *(const s16x8*)((const char*)&Ap[p][0] + boff);
            }
#pragma unroll
        for (int pb = 0; pb < 3; pb++) {
            s16x8 b0 = *(const s16x8*)&wm[((size_t)((pb * 4 + ks) * 8 + wave * 2)) * 512 + lane * 8];
            s16x8 b1 = *(const s16x8*)&wm[((size_t)((pb * 4 + ks) * 8 + wave * 2 + 1)) * 512 + lane * 8];
            int npa = 3 - pb;
#pragma unroll
            for (int pa = 0; pa < 3; pa++) {
                if (pa < npa) {
#pragma unroll
                    for (int mt = 0; mt < 4; mt++) {
                        acc[mt][0] = __builtin_amdgcn_mfma_f32_16x16x32_bf16(a[pa][mt], b0, acc[mt][0], 0, 0, 0);
                        acc[mt][1] = __builtin_amdgcn_mfma_f32_16x16x32_bf16(a[pa][mt], b1, acc[mt][1], 0, 0, 0);
                    }
                }
            }
        }
    }
#pragma unroll
    for (int mt = 0; mt < 4; mt++)
#pragma unroll
        for (int nt = 0; nt < 2; nt++) {
            int col = (wave * 2 + nt) * 16 + lr;
#pragma unroll
            for (int j = 0; j < 4; j++) {
                size_t row = nbase + mt * 16 + kg * 4 + j;
                if (row < NN_NODES) m[row * CC + col] = acc[mt][nt][j];
            }
        }
}

// ---------------- agg[n] = sum over in-edges of m[src] (fp32, as round 4) ----------------

__global__ __launch_bounds__(256) void gather_agg(const float* __restrict__ mbuf,
                                                  const int* __restrict__ offs,
                                                  const int* __restrict__ csr,
                                                  float* __restrict__ agg) {
    int tid = threadIdx.x;
    int node = blockIdx.x * 8 + (tid >> 5);
    int c4 = (tid & 31) << 2;
    int b = offs[node], e = offs[node + 1];
    float ax = 0.f, ay = 0.f, az = 0.f, aw = 0.f;
    for (int j = b; j < e; j++) {
        int s = csr[j];
        float4 v = *(const float4*)&mbuf[(size_t)s * CC + c4];
        ax += v.x; ay += v.y; az += v.z; aw += v.w;
    }
    *(float4*)&agg[(size_t)node * CC + c4] = make_float4(ax, ay, az, aw);
}

// ---------------- fused gates (bf16x3 MFMA) ----------------
// 32 nodes/block, 4 waves. Wave w owns r-tiles {2w,2w+1}, z {8+2w,9+2w}, n {16+2w,17+2w}
// (B cols: u<128 = r rows of wi/wh, u in [128,256) = z, u >= 256 = n).
// pass1: A = agg planes, B = gwi (r,z, i_n);  pass2: A = h planes, B = gwh (r,z, h_n).
// r/z accumulate across both passes (the K-concat sum); i_n / h_n kept separate.

__global__ __launch_bounds__(256, 3) void gates_mfma(const float* __restrict__ agg,
                                                     float* __restrict__ h,
                                                     const ushort* __restrict__ gwi,
                                                     const ushort* __restrict__ gwh,
                                                     const float* __restrict__ bpk,
                                                     int relu) {
    __shared__ ushort Aa[3][32 * 128];
    __shared__ ushort Ah[3][32 * 128];
    int tid = threadIdx.x;
    size_t nbase = (size_t)blockIdx.x * 32;
    const float4* ag = (const float4*)(agg + nbase * CC);
    const float4* hg = (const float4*)(h + nbase * CC);
#pragma unroll
    for (int i = 0; i < 4; i++) {
        int fi = tid + i * 256;            // 0..1023
        int row = fi >> 5;
        int boff = row * 256 + ((((fi & 31) * 8)) ^ ((row & 7) << 4));
        float4 va = ag[fi];
        float4 vh = hg[fi];
        ushort4 s1, s2, s3;
        split3(va.x, s1.x, s2.x, s3.x);
        split3(va.y, s1.y, s2.y, s3.y);
        split3(va.z, s1.z, s2.z, s3.z);
        split3(va.w, s1.w, s2.w, s3.w);
        *(ushort4*)((char*)&Aa[0][0] + boff) = s1;
        *(ushort4*)((char*)&Aa[1][0] + boff) = s2;
        *(ushort4*)((char*)&Aa[2][0] + boff) = s3;
        split3(vh.x, s1.x, s2.x, s3.x);
        split3(vh.y, s1.y, s2.y, s3.y);
        split3(vh.z, s1.z, s2.z, s3.z);
        split3(vh.w, s1.w, s2.w, s3.w);
        *(ushort4*)((char*)&Ah[0][0] + boff) = s1;
        *(ushort4*)((char*)&Ah[1][0] + boff) = s2;
        *(ushort4*)((char*)&Ah[2][0] + boff) = s3;
    }
    __syncthreads();
    int wave = tid >> 6, lane = tid & 63, lr = lane & 15, kg = lane >> 4;
    f32x4 accR[2][2] = {}, accZ[2][2] = {}, accN1[2][2] = {}, accN2[2][2] = {};
#pragma unroll
    for (int ks = 0; ks < 4; ks++) {
        s16x8 aA[3][2], aH[3][2];
#pragma unroll
        for (int p = 0; p < 3; p++)
#pragma unroll
            for (int mt = 0; mt < 2; mt++) {
                int row = mt * 16 + lr;
                int boff = row * 256 + ((ks * 64 + kg * 16) ^ ((row & 7) << 4));
                aA[p][mt] = *(const s16x8*)((const char*)&Aa[p][0] + boff);
                aH[p][mt] = *(const s16x8*)((const char*)&Ah[p][0] + boff);
            }
#pragma unroll
        for (int pb = 0; pb < 3; pb++) {
            int npa = 3 - pb;
            // ---- pass 1: A = agg, B = gwi ----
            {
                size_t cb = ((size_t)(pb * 4 + ks) * 24) * 512 + lane * 8;
                s16x8 br0 = *(const s16x8*)&gwi[cb + (size_t)(2 * wave) * 512];
                s16x8 br1 = *(const s16x8*)&gwi[cb + (size_t)(2 * wave + 1) * 512];
                s16x8 bz0 = *(const s16x8*)&gwi[cb + (size_t)(8 + 2 * wave) * 512];
                s16x8 bz1 = *(const s16x8*)&gwi[cb + (size_t)(9 + 2 * wave) * 512];
                s16x8 bn0 = *(const s16x8*)&gwi[cb + (size_t)(16 + 2 * wave) * 512];
                s16x8 bn1 = *(const s16x8*)&gwi[cb + (size_t)(17 + 2 * wave) * 512];
#pragma unroll
                for (int pa = 0; pa < 3; pa++) {
                    if (pa < npa) {
#pragma unroll
                        for (int mt = 0; mt < 2; mt++) {
                            accR[mt][0] = __builtin_amdgcn_mfma_f32_16x16x32_bf16(aA[pa][mt], br0, accR[mt][0], 0, 0, 0);
                            accR[mt][1] = __builtin_amdgcn_mfma_f32_16x16x32_bf16(aA[pa][mt], br1, accR[mt][1], 0, 0, 0);
                            accZ[mt][0] = __builtin_amdgcn_mfma_f32_16x16x32_bf16(aA[pa][mt], bz0, accZ[mt][0], 0, 0, 0);
                            accZ[mt][1] = __builtin_amdgcn_mfma_f32_16x16x32_bf16(aA[pa][mt], bz1, accZ[mt][1], 0, 0, 0);
                            accN1[mt][0] = __builtin_amdgcn_mfma_f32_16x16x32_bf16(aA[pa][mt], bn0, accN1[mt][0], 0, 0, 0);
                            accN1[mt][1] = __builtin_amdgcn_mfma_f32_16x16x32_bf16(aA[pa][mt], bn1, accN1[mt][1], 0, 0, 0);
                        }
                    }
                }
            }
            // ---- pass 2: A = h, B = gwh ----
            {
                size_t cb = ((size_t)(pb * 4 + ks) * 24) * 512 + lane * 8;
                s16x8 br0 = *(const s16x8*)&gwh[cb + (size_t)(2 * wave) * 512];
                s16x8 br1 = *(const s16x8*)&gwh[cb + (size_t)(2 * wave + 1) * 512];
                s16x8 bz0 = *(const s16x8*)&gwh[cb + (size_t)(8 + 2 * wave) * 512];
                s16x8 bz1 = *(const s16x8*)&gwh[cb + (size_t)(9 + 2 * wave) * 512];
                s16x8 bn0 = *(const s16x8*)&gwh[cb + (size_t)(16 + 2 * wave) * 512];
                s16x8 bn1 = *(const s16x8*)&gwh[cb + (size_t)(17 + 2 * wave) * 512];
#pragma unroll
                for (int pa = 0; pa < 3; pa++) {
                    if (pa < npa) {
#pragma unroll
                        for (int mt = 0; mt < 2; mt++) {
                            accR[mt][0] = __builtin_amdgcn_mfma_f32_16x16x32_bf16(aH[pa][mt], br0, accR[mt][0], 0, 0, 0);
                            accR[mt][1] = __builtin_amdgcn_mfma_f32_16x16x32_bf16(aH[pa][mt], br1, accR[mt][1], 0, 0, 0);
                            accZ[mt][0] = __builtin_amdgcn_mfma_f32_16x16x32_bf16(aH[pa][mt], bz0, accZ[mt][0], 0, 0, 0);
                            accZ[mt][1] = __builtin_amdgcn_mfma_f32_16x16x32_bf16(aH[pa][mt], bz1, accZ[mt][1], 0, 0, 0);
                            accN2[mt][0] = __builtin_amdgcn_mfma_f32_16x16x32_bf16(aH[pa][mt], bn0, accN2[mt][0], 0, 0, 0);
                            accN2[mt][1] = __builtin_amdgcn_mfma_f32_16x16x32_bf16(aH[pa][mt], bn1, accN2[mt][1], 0, 0, 0);
                        }
                    }
                }
            }
        }
    }
    // epilogue: lane lr holds col c = 32*wave + 16*t + lr for all four gate pre-activations
#pragma unroll
    for (int mt = 0; mt < 2; mt++)
#pragma unroll
        for (int t = 0; t < 2; t++) {
            int c = 32 * wave + 16 * t + lr;
            float4 bb = *(const float4*)&bpk[c * 4];
#pragma unroll
            for (int j = 0; j < 4; j++) {
                size_t row = nbase + mt * 16 + kg * 4 + j;
                float rr = 1.f / (1.f + expf(-(accR[mt][t][j] + bb.x)));
                float zz = 1.f / (1.f + expf(-(accZ[mt][t][j] + bb.y)));
                float nn = tanhf(accN1[mt][t][j] + bb.z + rr * (accN2[mt][t][j] + bb.w));
                float hold = h[row * CC + c];
                float v = (1.f - zz) * nn + zz * hold;
                if (relu) v = fmaxf(v, 0.f);
                h[row * CC + c] = v;
            }
        }
}

// ---------------- launch ----------------

extern "C" void kernel_launch(void* const* d_in, const int* in_sizes, int n_in,
                              void* d_out, int out_size, void* d_ws, size_t ws_size,
                              hipStream_t stream) {
    const float* x = (const float*)d_in[0];
    const int* ei = (const int*)d_in[1];
    const float* weights = (const float*)d_in[2];
    const float* w_ih = (const float*)d_in[3];
    const float* w_hh = (const float*)d_in[4];
    const float* b_ih = (const float*)d_in[5];
    const float* b_hh = (const float*)d_in[6];
    float* h = (float*)d_out;

    const int* src = ei;
    const int* dst = ei + NN_EDGES;

    // workspace carve
    float* mbuf = (float*)d_ws;                           // NN_PAD*128 fp32
    float* agg = mbuf + (size_t)NN_PAD * CC;              // NN_PAD*128 fp32
    float* bpack = agg + (size_t)NN_PAD * CC;             // NL*512
    float* endf = bpack + NL * 512;
    ushort* wm3 = (ushort*)endf;                          // 30*WM_LS
    ushort* gw3 = wm3 + (size_t)NL * NS * WM_LS;          // 6*GW_ML
    ushort* endu = gw3 + (size_t)6 * GW_ML;
    int* deg = (int*)endu;                                // 100000
    int* cursor = deg + NN_NODES;                         // 100000
    int* offsets = cursor + NN_NODES;                     // 100001
    int* csr = offsets + (NN_NODES + 1);                  // 600000
    int* partials = csr + NN_EDGES;                       // 99+

    hipMemcpyAsync(h, x, (size_t)NN_NODES * CC * sizeof(float),
                   hipMemcpyDeviceToDevice, stream);
    hipMemsetAsync(deg, 0, (size_t)2 * NN_NODES * sizeof(int), stream);

    const int EB = (NN_EDGES + 255) / 256;
    count_deg<<<EB, 256, 0, stream>>>(dst, deg);
    scan1<<<98, 256, 0, stream>>>(deg, offsets, partials);
    scan2<<<1, 128, 0, stream>>>(partials);
    scan3<<<98, 256, 0, stream>>>(offsets, partials);
    fill_csr<<<EB, 256, 0, stream>>>(src, dst, offsets, cursor, csr);
    pack_wm3<<<240, 256, 0, stream>>>(weights, wm3);
    pack_gw3<<<144, 256, 0, stream>>>(w_ih, w_hh, gw3);
    pack_bias_f32<<<6, 256, 0, stream>>>(b_ih, b_hh, bpack);

    const int GB_M = (NN_NODES + 63) / 64;   // 1563
    const int GB_GATH = NN_NODES / 8;        // 12500
    const int GB_GATES = NN_NODES / 32;      // 3125

    for (int l = 0; l < NL; l++) {
        for (int s = 0; s < NS; s++) {
            gemm_m_mfma<<<GB_M, 256, 0, stream>>>(
                h, wm3 + (size_t)(l * NS + s) * WM_LS, mbuf);
            gather_agg<<<GB_GATH, 256, 0, stream>>>(mbuf, offsets, csr, agg);
            int relu = (s == NS - 1 && l < NL - 1) ? 1 : 0;
            gates_mfma<<<GB_GATES, 256, 0, stream>>>(
                agg, h, gw3 + (size_t)l * GW_ML, gw3 + (size_t)(NL + l) * GW_ML,
                bpack + (size_t)l * 512, relu);
        }
    }
    (void)in_sizes; (void)n_in; (void)out_size; (void)ws_size;
}